// Round 21
// baseline (143.205 us; speedup 1.0000x reference)
//
#include <hip/hip_runtime.h>

#define NN 4681        // total nodes
#define NI 585         // internal (parent) nodes
#define KP 320         // K padded to multiple of 32

typedef __bf16 bf16x8 __attribute__((ext_vector_type(8)));
typedef float f32x4 __attribute__((ext_vector_type(4)));
typedef unsigned short u16x4 __attribute__((ext_vector_type(4)));

__device__ __forceinline__ float sigm(float x) { return 1.f / (1.f + expf(-x)); }

__device__ __forceinline__ unsigned short f2bf(float x) {
  unsigned u = __float_as_uint(x);
  u += 0x7FFFu + ((u >> 16) & 1u);
  return (unsigned short)(u >> 16);
}

__device__ __forceinline__ bf16x8 mk_frag(const unsigned short* lo, const unsigned short* hi) {
  union { u16x4 p[2]; bf16x8 v; } t;
  t.p[0] = *(const u16x4*)lo;
  t.p[1] = *(const u16x4*)hi;
  return t.v;
}

// ---------------- prep: bf16 weight transposes (K padded to 320 with zeros) ----------------
__global__ __launch_bounds__(256) void prep_kernel(
    const float* __restrict__ W_ioux, const float* __restrict__ W_fx,
    const float* __restrict__ W_fh, const float* __restrict__ W_iouh,
    unsigned short* __restrict__ WT, unsigned short* __restrict__ WfhT,
    unsigned short* __restrict__ WiouhT,
    unsigned short* __restrict__ h_bf, unsigned short* __restrict__ hsb_bf)
{
  const int bid = blockIdx.x, tid = threadIdx.x;
  if (bid < 1200) {
    const int c = bid;
    for (int k = tid; k < KP; k += 256) {
      float v = 0.f;
      if (k < 300) v = (c < 900) ? W_ioux[(size_t)k * 900 + c] : W_fx[(size_t)k * 300 + (c - 900)];
      WT[(size_t)c * KP + k] = f2bf(v);
    }
  } else if (bid < 1500) {
    const int c = bid - 1200;
    for (int k = tid; k < KP; k += 256) {
      float v = (k < 300) ? W_fh[(size_t)k * 300 + c] : 0.f;
      WfhT[(size_t)c * KP + k] = f2bf(v);
    }
  } else if (bid < 2400) {
    const int c = bid - 1500;
    for (int k = tid; k < KP; k += 256) {
      float v = (k < 300) ? W_iouh[(size_t)k * 900 + c] : 0.f;
      WiouhT[(size_t)c * KP + k] = f2bf(v);
    }
  } else if (bid < 2656) {
    const int r0 = (bid - 2400) * 16;
    for (int idx = tid; idx < 320; idx += 256) {
      const int r = r0 + idx / 20, k = 300 + idx % 20;
      h_bf[(size_t)r * KP + k] = 0;
    }
  } else {
    const int r0 = (bid - 2656) * 16;
    for (int idx = tid; idx < 320; idx += 256) {
      const int r = r0 + idx / 20, k = 300 + idx % 20;
      if (r < NI) hsb_bf[(size_t)r * KP + k] = 0;
    }
  }
}

// ---------------- MFMA X-GEMM (64x32 tile, 2 strips): internal -> xiou+fxo; leaf -> gates ----
__global__ __launch_bounds__(256) void fx_mfma(
    const int* __restrict__ tokens, const float* __restrict__ embed,
    const unsigned short* __restrict__ WT,
    const float* __restrict__ b_ioux, const float* __restrict__ b_fx,
    const float* __restrict__ b_iouh,
    float* __restrict__ xiou, float* __restrict__ fxo,
    float* __restrict__ c_cur, unsigned short* __restrict__ h_bf,
    float* __restrict__ hsb, unsigned short* __restrict__ hsb_bf)
{
  __shared__ unsigned short As[64][48];
  __shared__ unsigned short Bs[4][32][48];
  __shared__ int toks[64];
  const int tid = threadIdx.x;
  const int rt = blockIdx.x / 10, jt = blockIdx.x % 10;
  const bool leaf = (rt >= 10);
  const int R0 = leaf ? (585 + (rt - 10) * 64) : rt * 64;
  const int col0 = jt * 32;
  const int w = tid >> 6, lane = tid & 63, q = lane >> 4, cl = lane & 15;
  const int srow = tid >> 2, sk = (tid & 3) * 8;
  const int bph = tid >> 7, brem = tid & 127;          // B-stage: plane-half, col, chunk
  const int bcol = brem >> 2, bks = (brem & 3) * 8;

  if (tid < 64) toks[tid] = tokens[R0 + tid];

  f32x4 acc[2][4] = {};
  for (int kt = 0; kt < 10; ++kt) {
    const int k0 = kt * 32;
    __syncthreads();
    {
      const float* src = embed + (size_t)toks[srow] * 300;
      const int kb = k0 + sk;
      unsigned short tmp[8];
      if (kb + 7 < 300) {
        float4 v0 = *(const float4*)(src + kb);
        float4 v1 = *(const float4*)(src + kb + 4);
        tmp[0]=f2bf(v0.x); tmp[1]=f2bf(v0.y); tmp[2]=f2bf(v0.z); tmp[3]=f2bf(v0.w);
        tmp[4]=f2bf(v1.x); tmp[5]=f2bf(v1.y); tmp[6]=f2bf(v1.z); tmp[7]=f2bf(v1.w);
      } else {
#pragma unroll
        for (int e = 0; e < 8; ++e) tmp[e] = f2bf((kb + e < 300) ? src[kb + e] : 0.f);
      }
      *(u16x4*)&As[srow][sk]     = *(u16x4*)&tmp[0];
      *(u16x4*)&As[srow][sk + 4] = *(u16x4*)&tmp[4];
    }
    {
      const int cg = col0 + bcol;
#pragma unroll
      for (int ph = 0; ph < 2; ++ph) {
        const int p = 2 * bph + ph;
        uint4 wv = {0, 0, 0, 0};
        if (cg < 300 && (p < 3 || !leaf))
          wv = *(const uint4*)(WT + (size_t)(p * 300 + cg) * KP + k0 + bks);
        *(uint4*)&Bs[p][bcol][bks] = wv;
      }
    }
    __syncthreads();
    bf16x8 af = mk_frag(&As[16 * w + cl][4 * q], &As[16 * w + cl][16 + 4 * q]);
#pragma unroll
    for (int s = 0; s < 2; ++s) {
#pragma unroll
      for (int p = 0; p < 4; ++p) {
        if (!(p == 3 && leaf)) {
          bf16x8 bf = mk_frag(&Bs[p][16 * s + cl][4 * q], &Bs[p][16 * s + cl][16 + 4 * q]);
          acc[s][p] = __builtin_amdgcn_mfma_f32_16x16x32_bf16(af, bf, acc[s][p], 0, 0, 0);
        }
      }
    }
  }

#pragma unroll
  for (int s = 0; s < 2; ++s) {
    const int jj = col0 + 16 * s + cl;
    if (jj >= 300) continue;
    if (leaf) {
      const float bi = b_ioux[jj] + b_iouh[jj];
      const float bo = b_ioux[300 + jj] + b_iouh[300 + jj];
      const float bu = b_ioux[600 + jj] + b_iouh[600 + jj];
      float hsum = 0.f;
#pragma unroll
      for (int r = 0; r < 4; ++r) {
        const int rel = (R0 - 585) + 16 * w + 4 * q + r;
        float iv = acc[s][0][r] + bi, ov = acc[s][1][r] + bo, uv = acc[s][2][r] + bu;
        float cv = sigm(iv) * tanhf(uv);
        float hv = sigm(ov) * tanhf(cv);
        c_cur[(size_t)rel * 300 + jj] = cv;
        h_bf[(size_t)rel * KP + jj] = f2bf(hv);
        hsum += hv;
      }
      float tot = hsum + __shfl_xor(hsum, 16);
      if ((q & 1) == 0) {
        const int p = 73 + ((R0 - 585 + 16 * w) >> 3) + (q >> 1);
        hsb[(size_t)p * 300 + jj] = tot;
        hsb_bf[(size_t)p * KP + jj] = f2bf(tot);
      }
    } else {
#pragma unroll
      for (int r = 0; r < 4; ++r) {
        const int grow = R0 + 16 * w + 4 * q + r;
        if (grow < NI) {
          xiou[(size_t)grow * 900 + jj]       = acc[s][0][r] + b_ioux[jj];
          xiou[(size_t)grow * 900 + 300 + jj] = acc[s][1][r] + b_ioux[300 + jj];
          xiou[(size_t)grow * 900 + 600 + jj] = acc[s][2][r] + b_ioux[600 + jj];
          fxo[(size_t)grow * 300 + jj]        = acc[s][3][r] + b_fx[jj];
        }
      }
    }
  }
}

// ---------------- MFMA iou-GEMM + gates + h-sum (64x32, levels 512/64) ----------------
__global__ __launch_bounds__(256) void ig_mfma(
    int M, int start, int pstart,
    const unsigned short* __restrict__ hsb_bf_in, const unsigned short* __restrict__ WiouhT,
    const float* __restrict__ xiou, const float* __restrict__ b_iouh,
    const float* __restrict__ fcb_in,
    float* __restrict__ c_cur, unsigned short* __restrict__ h_bf,
    float* __restrict__ hsb, unsigned short* __restrict__ hsb_bf_out)
{
  __shared__ unsigned short As[64][48];
  __shared__ unsigned short Bs[3][32][48];
  const int tid = threadIdx.x;
  const int rt = blockIdx.x / 10, jt = blockIdx.x % 10;
  const int R0 = rt * 64;
  const int col0 = jt * 32;
  const int w = tid >> 6, lane = tid & 63, q = lane >> 4, cl = lane & 15;
  const int srow = tid >> 2, sk = (tid & 3) * 8;
  const int bcol2 = tid >> 3, bks2 = (tid & 7) * 4;    // 32 cols x 8 chunks of 4

  f32x4 acc[2][3] = {};
  for (int kt = 0; kt < 10; ++kt) {
    const int k0 = kt * 32;
    __syncthreads();
    *(uint4*)&As[srow][sk] = *(const uint4*)(hsb_bf_in + (size_t)(start + R0 + srow) * KP + k0 + sk);
    {
      const int cg = col0 + bcol2;
#pragma unroll
      for (int p = 0; p < 3; ++p) {
        u16x4 wv = {0, 0, 0, 0};
        if (cg < 300) wv = *(const u16x4*)(WiouhT + (size_t)(p * 300 + cg) * KP + k0 + bks2);
        *(u16x4*)&Bs[p][bcol2][bks2] = wv;
      }
    }
    __syncthreads();
    bf16x8 af = mk_frag(&As[16 * w + cl][4 * q], &As[16 * w + cl][16 + 4 * q]);
#pragma unroll
    for (int s = 0; s < 2; ++s) {
#pragma unroll
      for (int p = 0; p < 3; ++p) {
        bf16x8 bf = mk_frag(&Bs[p][16 * s + cl][4 * q], &Bs[p][16 * s + cl][16 + 4 * q]);
        acc[s][p] = __builtin_amdgcn_mfma_f32_16x16x32_bf16(af, bf, acc[s][p], 0, 0, 0);
      }
    }
  }

#pragma unroll
  for (int s = 0; s < 2; ++s) {
    const int jj = col0 + 16 * s + cl;
    if (jj >= 300) continue;
    float hsum = 0.f;
#pragma unroll
    for (int r = 0; r < 4; ++r) {
      const int rel = R0 + 16 * w + 4 * q + r;
      if (rel < M) {
        const int node = start + rel;
        float iv = acc[s][0][r] + xiou[(size_t)node * 900 + jj]       + b_iouh[jj];
        float ov = acc[s][1][r] + xiou[(size_t)node * 900 + 300 + jj] + b_iouh[300 + jj];
        float uv = acc[s][2][r] + xiou[(size_t)node * 900 + 600 + jj] + b_iouh[600 + jj];
        float cv = sigm(iv) * tanhf(uv) + fcb_in[(size_t)node * 300 + jj];
        float hv = sigm(ov) * tanhf(cv);
        c_cur[(size_t)rel * 300 + jj] = cv;
        h_bf[(size_t)rel * KP + jj] = f2bf(hv);
        hsum += hv;
      }
    }
    float tot = hsum + __shfl_xor(hsum, 16);
    if ((q & 1) == 0 && (R0 + 16 * w + (q >> 1) * 8) < M) {
      const int p = pstart + ((R0 + 16 * w) >> 3) + (q >> 1);
      hsb[(size_t)p * 300 + jj] = tot;
      hsb_bf_out[(size_t)p * KP + jj] = f2bf(tot);
    }
  }
}

// ---------------- MFMA W_fh + f-gate + fc reduction (64x32, leaf + 512) ----------------
__global__ __launch_bounds__(256) void fcb_mfma(
    int M, int pstart,
    const unsigned short* __restrict__ h_bf, const unsigned short* __restrict__ WfhT,
    const float* __restrict__ c_cur, const float* __restrict__ b_fh,
    const float* __restrict__ fxo, float* __restrict__ fcb)
{
  __shared__ unsigned short As[64][48];
  __shared__ unsigned short Bs[32][48];
  const int tid = threadIdx.x;
  const int rt = blockIdx.x / 10, jt = blockIdx.x % 10;
  const int R0 = rt * 64;
  const int col0 = jt * 32;
  const int w = tid >> 6, lane = tid & 63, q = lane >> 4, cl = lane & 15;
  const int srow = tid >> 2, sk = (tid & 3) * 8;
  const int bcol2 = tid >> 3, bks2 = (tid & 7) * 4;

  f32x4 acc[2] = {{0,0,0,0},{0,0,0,0}};
  for (int kt = 0; kt < 10; ++kt) {
    const int k0 = kt * 32;
    __syncthreads();
    *(uint4*)&As[srow][sk] = *(const uint4*)(h_bf + (size_t)(R0 + srow) * KP + k0 + sk);
    {
      const int cg = col0 + bcol2;
      u16x4 wv = {0, 0, 0, 0};
      if (cg < 300) wv = *(const u16x4*)(WfhT + (size_t)cg * KP + k0 + bks2);
      *(u16x4*)&Bs[bcol2][bks2] = wv;
    }
    __syncthreads();
    bf16x8 af = mk_frag(&As[16 * w + cl][4 * q], &As[16 * w + cl][16 + 4 * q]);
#pragma unroll
    for (int s = 0; s < 2; ++s) {
      bf16x8 bf = mk_frag(&Bs[16 * s + cl][4 * q], &Bs[16 * s + cl][16 + 4 * q]);
      acc[s] = __builtin_amdgcn_mfma_f32_16x16x32_bf16(af, bf, acc[s], 0, 0, 0);
    }
  }

#pragma unroll
  for (int s = 0; s < 2; ++s) {
    const int jj = col0 + 16 * s + cl;
    if (jj >= 300) continue;
    const int p = pstart + ((R0 + 16 * w) >> 3) + (q >> 1);
    float fc = 0.f;
#pragma unroll
    for (int r = 0; r < 4; ++r) {
      const int rel = R0 + 16 * w + 4 * q + r;
      if (rel < M) {
        const float add = b_fh[jj] + fxo[(size_t)p * 300 + jj];
        float f = sigm(acc[s][r] + add);
        fc += f * c_cur[(size_t)rel * 300 + jj];
      }
    }
    float tot = fc + __shfl_xor(fc, 16);
    if ((q & 1) == 0 && (R0 + 16 * w + (q >> 1) * 8) < M)
      fcb[(size_t)p * 300 + jj] = tot;
  }
}

// ================= 16-col shared bodies (verbatim, proven r20) — used by t5/t6 only ========
__device__ __forceinline__ void ig_body(
    unsigned short As[64][48], unsigned short Bs[3][16][48],
    int jt, int M, int start, int pstart,
    const unsigned short* __restrict__ hsb_bf_in, const unsigned short* __restrict__ WiouhT,
    const float* __restrict__ xiou, const float* __restrict__ b_iouh,
    const float* __restrict__ fcb_in,
    float* __restrict__ c_cur, unsigned short* __restrict__ h_bf,
    float* __restrict__ hsb, unsigned short* __restrict__ hsb_bf_out,
    float* __restrict__ root_out)
{
  const int tid = threadIdx.x;
  const int j0 = jt * 16;
  const int w = tid >> 6, lane = tid & 63, q = lane >> 4, cl = lane & 15;
  const int srow = tid >> 2, sk = (tid & 3) * 8;
  const int bp = tid >> 6, bcol = (tid >> 2) & 15;

  f32x4 acc[3] = {{0,0,0,0},{0,0,0,0},{0,0,0,0}};
  for (int kt = 0; kt < 10; ++kt) {
    const int k0 = kt * 32;
    __syncthreads();
    *(uint4*)&As[srow][sk] = *(const uint4*)(hsb_bf_in + (size_t)(start + srow) * KP + k0 + sk);
    if (bp < 3) {
      uint4 wv = {0, 0, 0, 0};
      const int cg = j0 + bcol;
      if (cg < 300) wv = *(const uint4*)(WiouhT + (size_t)(bp * 300 + cg) * KP + k0 + sk);
      *(uint4*)&Bs[bp][bcol][sk] = wv;
    }
    __syncthreads();
    bf16x8 af = mk_frag(&As[16 * w + cl][4 * q], &As[16 * w + cl][16 + 4 * q]);
#pragma unroll
    for (int p = 0; p < 3; ++p) {
      bf16x8 bf = mk_frag(&Bs[p][cl][4 * q], &Bs[p][cl][16 + 4 * q]);
      acc[p] = __builtin_amdgcn_mfma_f32_16x16x32_bf16(af, bf, acc[p], 0, 0, 0);
    }
  }

  const int jj = j0 + cl;
  if (jj >= 300) return;
  float hsum = 0.f;
#pragma unroll
  for (int r = 0; r < 4; ++r) {
    const int rel = 16 * w + 4 * q + r;
    if (rel < M) {
      const int node = start + rel;
      float iv = acc[0][r] + xiou[(size_t)node * 900 + jj]       + b_iouh[jj];
      float ov = acc[1][r] + xiou[(size_t)node * 900 + 300 + jj] + b_iouh[300 + jj];
      float uv = acc[2][r] + xiou[(size_t)node * 900 + 600 + jj] + b_iouh[600 + jj];
      float cv = sigm(iv) * tanhf(uv) + fcb_in[(size_t)node * 300 + jj];
      float hv = sigm(ov) * tanhf(cv);
      c_cur[(size_t)rel * 300 + jj] = cv;
      if (root_out) root_out[42 + jj] = hv;
      else          h_bf[(size_t)rel * KP + jj] = f2bf(hv);
      hsum += hv;
    }
  }
  float tot = hsum + __shfl_xor(hsum, 16);
  if ((q & 1) == 0 && (16 * w + (q >> 1) * 8) < M) {
    const int p = pstart + (16 * w >> 3) + (q >> 1);
    hsb[(size_t)p * 300 + jj] = tot;
    hsb_bf_out[(size_t)p * KP + jj] = f2bf(tot);
  }
}

__device__ __forceinline__ void fcb_body(
    unsigned short As[64][48], unsigned short Bsf[16][48],
    int jt, int M, int pstart,
    const unsigned short* __restrict__ h_bf, const unsigned short* __restrict__ WfhT,
    const float* __restrict__ c_cur, const float* __restrict__ b_fh,
    const float* __restrict__ fxo, float* __restrict__ fcb)
{
  const int tid = threadIdx.x;
  const int j0 = jt * 16;
  const int w = tid >> 6, lane = tid & 63, q = lane >> 4, cl = lane & 15;
  const int srow = tid >> 2, sk = (tid & 3) * 8;

  f32x4 acc = {0, 0, 0, 0};
  for (int kt = 0; kt < 10; ++kt) {
    const int k0 = kt * 32;
    __syncthreads();
    *(uint4*)&As[srow][sk] = *(const uint4*)(h_bf + (size_t)srow * KP + k0 + sk);
    if (tid < 64) {
      const int col = tid >> 2, ks = (tid & 3) * 8;
      uint4 wv = {0, 0, 0, 0};
      const int cg = j0 + col;
      if (cg < 300) wv = *(const uint4*)(WfhT + (size_t)cg * KP + k0 + ks);
      *(uint4*)&Bsf[col][ks] = wv;
    }
    __syncthreads();
    bf16x8 af = mk_frag(&As[16 * w + cl][4 * q], &As[16 * w + cl][16 + 4 * q]);
    bf16x8 bf = mk_frag(&Bsf[cl][4 * q], &Bsf[cl][16 + 4 * q]);
    acc = __builtin_amdgcn_mfma_f32_16x16x32_bf16(af, bf, acc, 0, 0, 0);
  }

  const int jj = j0 + cl;
  if (jj >= 300) return;
  const int p = pstart + (16 * w >> 3) + (q >> 1);
  float fc = 0.f;
#pragma unroll
  for (int r = 0; r < 4; ++r) {
    const int rel = 16 * w + 4 * q + r;
    if (rel < M) {
      const float add = b_fh[jj] + fxo[(size_t)p * 300 + jj];
      float f = sigm(acc[r] + add);
      fc += f * c_cur[(size_t)rel * 300 + jj];
    }
  }
  float tot = fc + __shfl_xor(fc, 16);
  if ((q & 1) == 0 && (16 * w + (q >> 1) * 8) < M)
    fcb[(size_t)p * 300 + jj] = tot;
}

// ---------------- merged: fcb64 then ig8 (-> rows 64..71), 19 blocks ----------------
__global__ __launch_bounds__(256) void t5_kernel(
    const unsigned short* __restrict__ h_bf, const unsigned short* __restrict__ WfhT,
    const float* __restrict__ c_cur, const float* __restrict__ b_fh,
    const float* __restrict__ fxo, float* __restrict__ fcb,
    const unsigned short* __restrict__ hsb_bf, const unsigned short* __restrict__ WiouhT,
    const float* __restrict__ xiou, const float* __restrict__ b_iouh,
    float* __restrict__ c_out, unsigned short* __restrict__ h_out,
    float* __restrict__ hsb, unsigned short* __restrict__ hsb_bf_out)
{
  __shared__ unsigned short As[64][48];
  __shared__ unsigned short Bs[3][16][48];
  const int jt = blockIdx.x;
  fcb_body(As, Bs[0], jt, 64, 1, h_bf, WfhT, c_cur, b_fh, fxo, fcb);
  __syncthreads();
  ig_body(As, Bs, jt, 8, 1, 0, hsb_bf, WiouhT, xiou, b_iouh, fcb,
          c_out, h_out, hsb, hsb_bf_out, nullptr);
}

// ---------------- merged: fcb8 then root iou/gates (-> out, c row 72), 19 blocks ----------
__global__ __launch_bounds__(256) void t6_kernel(
    const unsigned short* __restrict__ h_bf64, const unsigned short* __restrict__ WfhT,
    const float* __restrict__ c_cur64, const float* __restrict__ b_fh,
    const float* __restrict__ fxo, float* __restrict__ fcb,
    const unsigned short* __restrict__ hsb_bf, const unsigned short* __restrict__ WiouhT,
    const float* __restrict__ xiou, const float* __restrict__ b_iouh,
    float* __restrict__ c_root, float* __restrict__ hsb,
    unsigned short* __restrict__ hsb_bf_scratch, float* __restrict__ out)
{
  __shared__ unsigned short As[64][48];
  __shared__ unsigned short Bs[3][16][48];
  const int jt = blockIdx.x;
  fcb_body(As, Bs[0], jt, 8, 0, h_bf64, WfhT, c_cur64, b_fh, fxo, fcb);
  __syncthreads();
  ig_body(As, Bs, jt, 1, 0, 584, hsb_bf, WiouhT, xiou, b_iouh, fcb,
          c_root, nullptr, hsb, hsb_bf_scratch, out);
}

// ---------------- head: out[0..41] = c_root @ W_lin + b_lin (k-parallel) ----------------
__global__ __launch_bounds__(256) void head_kernel(
    const float* __restrict__ c_root, const float* __restrict__ W_lin,
    const float* __restrict__ b_lin, float* __restrict__ out)
{
  __shared__ float part[6][44];
  const int tid = threadIdx.x;
  if (tid < 252) {
    const int col = tid / 6, grp = tid % 6;
    float acc = 0.f;
    for (int k = grp * 50; k < grp * 50 + 50; ++k)
      acc += c_root[k] * W_lin[(size_t)k * 42 + col];
    part[grp][col] = acc;
  }
  __syncthreads();
  if (tid < 42) {
    float acc = b_lin[tid];
#pragma unroll
    for (int g = 0; g < 6; ++g) acc += part[g][tid];
    out[tid] = acc;
  }
}

extern "C" void kernel_launch(void* const* d_in, const int* in_sizes, int n_in,
                              void* d_out, int out_size, void* d_ws, size_t ws_size,
                              hipStream_t stream) {
  const int* tokens   = (const int*)d_in[0];
  const float* embed  = (const float*)d_in[3];
  const float* W_ioux = (const float*)d_in[4];
  const float* b_ioux = (const float*)d_in[5];
  const float* W_iouh = (const float*)d_in[6];
  const float* b_iouh = (const float*)d_in[7];
  const float* W_fx   = (const float*)d_in[8];
  const float* b_fx   = (const float*)d_in[9];
  const float* W_fh   = (const float*)d_in[10];
  const float* b_fh   = (const float*)d_in[11];
  const float* W_lin  = (const float*)d_in[12];
  const float* b_lin  = (const float*)d_in[13];
  float* out = (float*)d_out;

  float* ws    = (float*)d_ws;
  float* xiou  = ws;                                 // 585*900
  float* fxo   = xiou  + (size_t)NI * 900;           // 585*300
  float* hsb   = fxo   + (size_t)NI * 300;           // 585*300
  float* fcb   = hsb   + (size_t)NI * 300;           // 585*300
  float* c_cur = fcb   + (size_t)NI * 300;           // 4096*300 (rows 64..72 reused by tail)
  unsigned short* h_bf   = (unsigned short*)(c_cur + (size_t)4096 * 300);  // 4096*320
  unsigned short* WT     = h_bf   + (size_t)4096 * KP;   // 1200*320
  unsigned short* WfhT   = WT     + (size_t)1200 * KP;   // 300*320
  unsigned short* WiouhT = WfhT   + (size_t)300 * KP;    // 900*320
  unsigned short* hsb_bf = WiouhT + (size_t)900 * KP;    // 585*320

  // P: bf16 weight transposes + pads
  prep_kernel<<<2693, 256, 0, stream>>>(W_ioux, W_fx, W_fh, W_iouh,
      WT, WfhT, WiouhT, h_bf, hsb_bf);
  // K0: MFMA X-GEMM, 64x32 tiles (74 row-tiles x 10 col-tiles)
  fx_mfma<<<74 * 10, 256, 0, stream>>>(tokens, embed, WT, b_ioux, b_fx, b_iouh,
      xiou, fxo, c_cur, h_bf, hsb, hsb_bf);
  // K1: fcb leaf (4096 children -> parents 73..584), 64x10
  fcb_mfma<<<64 * 10, 256, 0, stream>>>(4096, 73, h_bf, WfhT, c_cur, b_fh, fxo, fcb);
  // K2: ig 512 (nodes 73..584 -> parents 9..72), 8x10; h/c rows 0..511
  ig_mfma<<<8 * 10, 256, 0, stream>>>(512, 73, 9, hsb_bf, WiouhT, xiou, b_iouh, fcb,
      c_cur, h_bf, hsb, hsb_bf);
  // K3: fcb 512, 8x10
  fcb_mfma<<<8 * 10, 256, 0, stream>>>(512, 9, h_bf, WfhT, c_cur, b_fh, fxo, fcb);
  // K4: ig 64 (nodes 9..72 -> parents 1..8), 1x10; h/c rows 0..63
  ig_mfma<<<10, 256, 0, stream>>>(64, 9, 1, hsb_bf, WiouhT, xiou, b_iouh, fcb,
      c_cur, h_bf, hsb, hsb_bf);
  // K5: merged fcb64 + ig8 (nodes 1..8); h/c -> rows 64..71
  t5_kernel<<<19, 256, 0, stream>>>(h_bf, WfhT, c_cur, b_fh, fxo, fcb,
      hsb_bf, WiouhT, xiou, b_iouh,
      c_cur + (size_t)64 * 300, h_bf + (size_t)64 * KP, hsb, hsb_bf);
  // K6: merged fcb8 + root iou/gates; root h -> out[42..], c_root -> row 72
  t6_kernel<<<19, 256, 0, stream>>>(h_bf + (size_t)64 * KP, WfhT,
      c_cur + (size_t)64 * 300, b_fh, fxo, fcb,
      hsb_bf, WiouhT, xiou, b_iouh,
      c_cur + (size_t)72 * 300, hsb, hsb_bf, out);
  // K7: W_lin head -> out[0..41]
  head_kernel<<<1, 256, 0, stream>>>(c_cur + (size_t)72 * 300, W_lin, b_lin, out);
}

// Round 22
// 121.807 us; speedup vs baseline: 1.1757x; 1.1757x over previous
//
#include <hip/hip_runtime.h>

#define NN 4681        // total nodes
#define NI 585         // internal (parent) nodes
#define KP 320         // K padded to multiple of 32

typedef __bf16 bf16x8 __attribute__((ext_vector_type(8)));
typedef float f32x4 __attribute__((ext_vector_type(4)));
typedef unsigned short u16x4 __attribute__((ext_vector_type(4)));

__device__ __forceinline__ float sigm(float x) { return 1.f / (1.f + expf(-x)); }

__device__ __forceinline__ unsigned short f2bf(float x) {
  unsigned u = __float_as_uint(x);
  u += 0x7FFFu + ((u >> 16) & 1u);
  return (unsigned short)(u >> 16);
}

__device__ __forceinline__ bf16x8 mk_frag(const unsigned short* lo, const unsigned short* hi) {
  union { u16x4 p[2]; bf16x8 v; } t;
  t.p[0] = *(const u16x4*)lo;
  t.p[1] = *(const u16x4*)hi;
  return t.v;
}

// ---------------- prep: bf16 weight transposes (K padded to 320 with zeros) ----------------
__global__ __launch_bounds__(256) void prep_kernel(
    const float* __restrict__ W_ioux, const float* __restrict__ W_fx,
    const float* __restrict__ W_fh, const float* __restrict__ W_iouh,
    unsigned short* __restrict__ WT, unsigned short* __restrict__ WfhT,
    unsigned short* __restrict__ WiouhT,
    unsigned short* __restrict__ h_bf, unsigned short* __restrict__ hsb_bf)
{
  const int bid = blockIdx.x, tid = threadIdx.x;
  if (bid < 1200) {
    const int c = bid;
    for (int k = tid; k < KP; k += 256) {
      float v = 0.f;
      if (k < 300) v = (c < 900) ? W_ioux[(size_t)k * 900 + c] : W_fx[(size_t)k * 300 + (c - 900)];
      WT[(size_t)c * KP + k] = f2bf(v);
    }
  } else if (bid < 1500) {
    const int c = bid - 1200;
    for (int k = tid; k < KP; k += 256) {
      float v = (k < 300) ? W_fh[(size_t)k * 300 + c] : 0.f;
      WfhT[(size_t)c * KP + k] = f2bf(v);
    }
  } else if (bid < 2400) {
    const int c = bid - 1500;
    for (int k = tid; k < KP; k += 256) {
      float v = (k < 300) ? W_iouh[(size_t)k * 900 + c] : 0.f;
      WiouhT[(size_t)c * KP + k] = f2bf(v);
    }
  } else if (bid < 2656) {
    const int r0 = (bid - 2400) * 16;
    for (int idx = tid; idx < 320; idx += 256) {
      const int r = r0 + idx / 20, k = 300 + idx % 20;
      h_bf[(size_t)r * KP + k] = 0;
    }
  } else {
    const int r0 = (bid - 2656) * 16;
    for (int idx = tid; idx < 320; idx += 256) {
      const int r = r0 + idx / 20, k = 300 + idx % 20;
      if (r < NI) hsb_bf[(size_t)r * KP + k] = 0;
    }
  }
}

// ---------------- MFMA X-GEMM: internal -> xiou+fxo; leaf -> gates+c/h+hsb ----------------
__global__ __launch_bounds__(256) void fx_mfma(
    const int* __restrict__ tokens, const float* __restrict__ embed,
    const unsigned short* __restrict__ WT,
    const float* __restrict__ b_ioux, const float* __restrict__ b_fx,
    const float* __restrict__ b_iouh,
    float* __restrict__ xiou, float* __restrict__ fxo,
    float* __restrict__ c_cur, unsigned short* __restrict__ h_bf,
    float* __restrict__ hsb, unsigned short* __restrict__ hsb_bf)
{
  __shared__ unsigned short As[64][48];
  __shared__ unsigned short Bs[4][16][48];
  __shared__ int toks[64];
  const int tid = threadIdx.x;
  const int rt = blockIdx.x / 19, jt = blockIdx.x % 19;
  const bool leaf = (rt >= 10);
  const int R0 = leaf ? (585 + (rt - 10) * 64) : rt * 64;
  const int j0 = jt * 16;
  const int w = tid >> 6, lane = tid & 63, q = lane >> 4, cl = lane & 15;
  const int srow = tid >> 2, sk = (tid & 3) * 8;
  const int bp = tid >> 6, bcol = (tid >> 2) & 15;

  if (tid < 64) toks[tid] = tokens[R0 + tid];

  f32x4 acc[4] = {{0,0,0,0},{0,0,0,0},{0,0,0,0},{0,0,0,0}};
  for (int kt = 0; kt < 10; ++kt) {
    const int k0 = kt * 32;
    __syncthreads();
    {
      const float* src = embed + (size_t)toks[srow] * 300;
      const int kb = k0 + sk;
      unsigned short tmp[8];
      if (kb + 7 < 300) {
        float4 v0 = *(const float4*)(src + kb);
        float4 v1 = *(const float4*)(src + kb + 4);
        tmp[0]=f2bf(v0.x); tmp[1]=f2bf(v0.y); tmp[2]=f2bf(v0.z); tmp[3]=f2bf(v0.w);
        tmp[4]=f2bf(v1.x); tmp[5]=f2bf(v1.y); tmp[6]=f2bf(v1.z); tmp[7]=f2bf(v1.w);
      } else {
#pragma unroll
        for (int e = 0; e < 8; ++e) tmp[e] = f2bf((kb + e < 300) ? src[kb + e] : 0.f);
      }
      *(u16x4*)&As[srow][sk]     = *(u16x4*)&tmp[0];
      *(u16x4*)&As[srow][sk + 4] = *(u16x4*)&tmp[4];
    }
    {
      uint4 wv = {0, 0, 0, 0};
      const int cg = j0 + bcol;
      if (cg < 300 && (bp < 3 || !leaf))
        wv = *(const uint4*)(WT + (size_t)(bp * 300 + cg) * KP + k0 + sk);
      *(uint4*)&Bs[bp][bcol][sk] = wv;
    }
    __syncthreads();
    bf16x8 af = mk_frag(&As[16 * w + cl][4 * q], &As[16 * w + cl][16 + 4 * q]);
#pragma unroll
    for (int p = 0; p < 4; ++p) {
      if (!(p == 3 && leaf)) {
        bf16x8 bf = mk_frag(&Bs[p][cl][4 * q], &Bs[p][cl][16 + 4 * q]);
        acc[p] = __builtin_amdgcn_mfma_f32_16x16x32_bf16(af, bf, acc[p], 0, 0, 0);
      }
    }
  }

  const int jj = j0 + cl;
  if (jj >= 300) return;
  if (leaf) {
    const float bi = b_ioux[jj] + b_iouh[jj];
    const float bo = b_ioux[300 + jj] + b_iouh[300 + jj];
    const float bu = b_ioux[600 + jj] + b_iouh[600 + jj];
    float hsum = 0.f;
#pragma unroll
    for (int r = 0; r < 4; ++r) {
      const int rel = (R0 - 585) + 16 * w + 4 * q + r;
      float iv = acc[0][r] + bi, ov = acc[1][r] + bo, uv = acc[2][r] + bu;
      float cv = sigm(iv) * tanhf(uv);
      float hv = sigm(ov) * tanhf(cv);
      c_cur[(size_t)rel * 300 + jj] = cv;
      h_bf[(size_t)rel * KP + jj] = f2bf(hv);
      hsum += hv;
    }
    float tot = hsum + __shfl_xor(hsum, 16);
    if ((q & 1) == 0) {
      const int p = 73 + ((R0 - 585 + 16 * w) >> 3) + (q >> 1);
      hsb[(size_t)p * 300 + jj] = tot;
      hsb_bf[(size_t)p * KP + jj] = f2bf(tot);
    }
  } else {
#pragma unroll
    for (int r = 0; r < 4; ++r) {
      const int grow = R0 + 16 * w + 4 * q + r;
      if (grow < NI) {
        xiou[(size_t)grow * 900 + jj]       = acc[0][r] + b_ioux[jj];
        xiou[(size_t)grow * 900 + 300 + jj] = acc[1][r] + b_ioux[300 + jj];
        xiou[(size_t)grow * 900 + 600 + jj] = acc[2][r] + b_ioux[600 + jj];
        fxo[(size_t)grow * 300 + jj]        = acc[3][r] + b_fx[jj];
      }
    }
  }
}

// ================= shared device bodies (verbatim, proven) =================
// root_out == nullptr: normal (write h_out row). root_out set: h -> root_out[42+jj].
__device__ __forceinline__ void ig_body(
    unsigned short As[64][48], unsigned short Bs[3][16][48],
    int jt, int M, int start, int pstart,
    const unsigned short* __restrict__ hsb_bf_in, const unsigned short* __restrict__ WiouhT,
    const float* __restrict__ xiou, const float* __restrict__ b_iouh,
    const float* __restrict__ fcb_in,
    float* __restrict__ c_cur, unsigned short* __restrict__ h_bf,
    float* __restrict__ hsb, unsigned short* __restrict__ hsb_bf_out,
    float* __restrict__ root_out)
{
  const int tid = threadIdx.x;
  const int j0 = jt * 16;
  const int w = tid >> 6, lane = tid & 63, q = lane >> 4, cl = lane & 15;
  const int srow = tid >> 2, sk = (tid & 3) * 8;
  const int bp = tid >> 6, bcol = (tid >> 2) & 15;

  f32x4 acc[3] = {{0,0,0,0},{0,0,0,0},{0,0,0,0}};
  for (int kt = 0; kt < 10; ++kt) {
    const int k0 = kt * 32;
    __syncthreads();
    *(uint4*)&As[srow][sk] = *(const uint4*)(hsb_bf_in + (size_t)(start + srow) * KP + k0 + sk);
    if (bp < 3) {
      uint4 wv = {0, 0, 0, 0};
      const int cg = j0 + bcol;
      if (cg < 300) wv = *(const uint4*)(WiouhT + (size_t)(bp * 300 + cg) * KP + k0 + sk);
      *(uint4*)&Bs[bp][bcol][sk] = wv;
    }
    __syncthreads();
    bf16x8 af = mk_frag(&As[16 * w + cl][4 * q], &As[16 * w + cl][16 + 4 * q]);
#pragma unroll
    for (int p = 0; p < 3; ++p) {
      bf16x8 bf = mk_frag(&Bs[p][cl][4 * q], &Bs[p][cl][16 + 4 * q]);
      acc[p] = __builtin_amdgcn_mfma_f32_16x16x32_bf16(af, bf, acc[p], 0, 0, 0);
    }
  }

  const int jj = j0 + cl;
  if (jj >= 300) return;
  float hsum = 0.f;
#pragma unroll
  for (int r = 0; r < 4; ++r) {
    const int rel = 16 * w + 4 * q + r;
    if (rel < M) {
      const int node = start + rel;
      float iv = acc[0][r] + xiou[(size_t)node * 900 + jj]       + b_iouh[jj];
      float ov = acc[1][r] + xiou[(size_t)node * 900 + 300 + jj] + b_iouh[300 + jj];
      float uv = acc[2][r] + xiou[(size_t)node * 900 + 600 + jj] + b_iouh[600 + jj];
      float cv = sigm(iv) * tanhf(uv) + fcb_in[(size_t)node * 300 + jj];
      float hv = sigm(ov) * tanhf(cv);
      c_cur[(size_t)rel * 300 + jj] = cv;
      if (root_out) root_out[42 + jj] = hv;
      else          h_bf[(size_t)rel * KP + jj] = f2bf(hv);
      hsum += hv;
    }
  }
  float tot = hsum + __shfl_xor(hsum, 16);
  if ((q & 1) == 0 && (16 * w + (q >> 1) * 8) < M) {
    const int p = pstart + (16 * w >> 3) + (q >> 1);
    hsb[(size_t)p * 300 + jj] = tot;
    hsb_bf_out[(size_t)p * KP + jj] = f2bf(tot);
  }
}

__device__ __forceinline__ void fcb_body(
    unsigned short As[64][48], unsigned short Bsf[16][48],
    int jt, int M, int pstart,
    const unsigned short* __restrict__ h_bf, const unsigned short* __restrict__ WfhT,
    const float* __restrict__ c_cur, const float* __restrict__ b_fh,
    const float* __restrict__ fxo, float* __restrict__ fcb)
{
  const int tid = threadIdx.x;
  const int j0 = jt * 16;
  const int w = tid >> 6, lane = tid & 63, q = lane >> 4, cl = lane & 15;
  const int srow = tid >> 2, sk = (tid & 3) * 8;

  f32x4 acc = {0, 0, 0, 0};
  for (int kt = 0; kt < 10; ++kt) {
    const int k0 = kt * 32;
    __syncthreads();
    *(uint4*)&As[srow][sk] = *(const uint4*)(h_bf + (size_t)srow * KP + k0 + sk);
    if (tid < 64) {
      const int col = tid >> 2, ks = (tid & 3) * 8;
      uint4 wv = {0, 0, 0, 0};
      const int cg = j0 + col;
      if (cg < 300) wv = *(const uint4*)(WfhT + (size_t)cg * KP + k0 + ks);
      *(uint4*)&Bsf[col][ks] = wv;
    }
    __syncthreads();
    bf16x8 af = mk_frag(&As[16 * w + cl][4 * q], &As[16 * w + cl][16 + 4 * q]);
    bf16x8 bf = mk_frag(&Bsf[cl][4 * q], &Bsf[cl][16 + 4 * q]);
    acc = __builtin_amdgcn_mfma_f32_16x16x32_bf16(af, bf, acc, 0, 0, 0);
  }

  const int jj = j0 + cl;
  if (jj >= 300) return;
  const int p = pstart + (16 * w >> 3) + (q >> 1);
  float fc = 0.f;
#pragma unroll
  for (int r = 0; r < 4; ++r) {
    const int rel = 16 * w + 4 * q + r;
    if (rel < M) {
      const float add = b_fh[jj] + fxo[(size_t)p * 300 + jj];
      float f = sigm(acc[r] + add);
      fc += f * c_cur[(size_t)rel * 300 + jj];
    }
  }
  float tot = fc + __shfl_xor(fc, 16);
  if ((q & 1) == 0 && (16 * w + (q >> 1) * 8) < M)
    fcb[(size_t)p * 300 + jj] = tot;
}

// ---------------- MFMA ig (multi-block: levels 512 and 64) ----------------
__global__ __launch_bounds__(256) void ig_mfma(
    int M, int start, int pstart,
    const unsigned short* __restrict__ hsb_bf_in, const unsigned short* __restrict__ WiouhT,
    const float* __restrict__ xiou, const float* __restrict__ b_iouh,
    const float* __restrict__ fcb_in,
    float* __restrict__ c_cur, unsigned short* __restrict__ h_bf,
    float* __restrict__ hsb, unsigned short* __restrict__ hsb_bf_out)
{
  __shared__ unsigned short As[64][48];
  __shared__ unsigned short Bs[3][16][48];
  const int rt = blockIdx.x / 19, jt = blockIdx.x % 19;
  const int R0 = rt * 64;
  ig_body(As, Bs, jt, M - R0, start + R0, pstart + (R0 >> 3),
      hsb_bf_in, WiouhT, xiou, b_iouh, fcb_in,
      c_cur + (size_t)R0 * 300, h_bf + (size_t)R0 * KP, hsb, hsb_bf_out, nullptr);
}

// ---------------- MFMA fcb (multi-block: leaf + 512) ----------------
__global__ __launch_bounds__(256) void fcb_mfma(
    int M, int pstart,
    const unsigned short* __restrict__ h_bf, const unsigned short* __restrict__ WfhT,
    const float* __restrict__ c_cur, const float* __restrict__ b_fh,
    const float* __restrict__ fxo, float* __restrict__ fcb)
{
  __shared__ unsigned short As[64][48];
  __shared__ unsigned short Bsf[16][48];
  const int rt = blockIdx.x / 19, jt = blockIdx.x % 19;
  const int R0 = rt * 64;
  fcb_body(As, Bsf, jt, M - R0, pstart + (R0 >> 3),
      h_bf + (size_t)R0 * KP, WfhT, c_cur + (size_t)R0 * 300, b_fh, fxo, fcb);
}

// ---------------- merged: fcb64 (h rows 0..63 -> fcb[1..8]) then ig8 (-> rows 64..71) ----
__global__ __launch_bounds__(256) void t5_kernel(
    const unsigned short* __restrict__ h_bf, const unsigned short* __restrict__ WfhT,
    const float* __restrict__ c_cur, const float* __restrict__ b_fh,
    const float* __restrict__ fxo, float* __restrict__ fcb,
    const unsigned short* __restrict__ hsb_bf, const unsigned short* __restrict__ WiouhT,
    const float* __restrict__ xiou, const float* __restrict__ b_iouh,
    float* __restrict__ c_out, unsigned short* __restrict__ h_out,
    float* __restrict__ hsb, unsigned short* __restrict__ hsb_bf_out)
{
  __shared__ unsigned short As[64][48];
  __shared__ unsigned short Bs[3][16][48];
  const int jt = blockIdx.x;
  // phase 1: fcb level-64 (children rows 0..63, parents 1..8)
  fcb_body(As, Bs[0], jt, 64, 1, h_bf, WfhT, c_cur, b_fh, fxo, fcb);
  __syncthreads();
  // phase 2: ig level-8 (nodes 1..8 -> root). fcb[1..8][strip] from phase 1 (same block).
  ig_body(As, Bs, jt, 8, 1, 0, hsb_bf, WiouhT, xiou, b_iouh, fcb,
          c_out, h_out, hsb, hsb_bf_out, nullptr);
}

// ---------------- merged: fcb8 (h rows 64..71 -> fcb[0]) then ig_root (-> out, c row 72) ----
__global__ __launch_bounds__(256) void t6_kernel(
    const unsigned short* __restrict__ h_bf64, const unsigned short* __restrict__ WfhT,
    const float* __restrict__ c_cur64, const float* __restrict__ b_fh,
    const float* __restrict__ fxo, float* __restrict__ fcb,
    const unsigned short* __restrict__ hsb_bf, const unsigned short* __restrict__ WiouhT,
    const float* __restrict__ xiou, const float* __restrict__ b_iouh,
    float* __restrict__ c_root, float* __restrict__ hsb,
    unsigned short* __restrict__ hsb_bf_scratch, float* __restrict__ out)
{
  __shared__ unsigned short As[64][48];
  __shared__ unsigned short Bs[3][16][48];
  const int jt = blockIdx.x;
  // phase 1: fcb level-8 (children at rows 64..71 via shifted base, parent 0)
  fcb_body(As, Bs[0], jt, 8, 0, h_bf64, WfhT, c_cur64, b_fh, fxo, fcb);
  __syncthreads();
  // phase 2: root iou+gates (M=1, node 0). fcb[0][strip] from phase 1 (same block).
  ig_body(As, Bs, jt, 1, 0, 584, hsb_bf, WiouhT, xiou, b_iouh, fcb,
          c_root, nullptr, hsb, hsb_bf_scratch, out);
}

// ---------------- head: out[0..41] = c_root @ W_lin + b_lin (k-parallel) ----------------
__global__ __launch_bounds__(256) void head_kernel(
    const float* __restrict__ c_root, const float* __restrict__ W_lin,
    const float* __restrict__ b_lin, float* __restrict__ out)
{
  __shared__ float part[6][44];
  const int tid = threadIdx.x;
  if (tid < 252) {
    const int col = tid / 6, grp = tid % 6;
    float acc = 0.f;
    for (int k = grp * 50; k < grp * 50 + 50; ++k)
      acc += c_root[k] * W_lin[(size_t)k * 42 + col];
    part[grp][col] = acc;
  }
  __syncthreads();
  if (tid < 42) {
    float acc = b_lin[tid];
#pragma unroll
    for (int g = 0; g < 6; ++g) acc += part[g][tid];
    out[tid] = acc;
  }
}

extern "C" void kernel_launch(void* const* d_in, const int* in_sizes, int n_in,
                              void* d_out, int out_size, void* d_ws, size_t ws_size,
                              hipStream_t stream) {
  const int* tokens   = (const int*)d_in[0];
  const float* embed  = (const float*)d_in[3];
  const float* W_ioux = (const float*)d_in[4];
  const float* b_ioux = (const float*)d_in[5];
  const float* W_iouh = (const float*)d_in[6];
  const float* b_iouh = (const float*)d_in[7];
  const float* W_fx   = (const float*)d_in[8];
  const float* b_fx   = (const float*)d_in[9];
  const float* W_fh   = (const float*)d_in[10];
  const float* b_fh   = (const float*)d_in[11];
  const float* W_lin  = (const float*)d_in[12];
  const float* b_lin  = (const float*)d_in[13];
  float* out = (float*)d_out;

  float* ws    = (float*)d_ws;
  float* xiou  = ws;                                 // 585*900
  float* fxo   = xiou  + (size_t)NI * 900;           // 585*300
  float* hsb   = fxo   + (size_t)NI * 300;           // 585*300
  float* fcb   = hsb   + (size_t)NI * 300;           // 585*300
  float* c_cur = fcb   + (size_t)NI * 300;           // 4096*300 (rows 64..72 reused by tail)
  unsigned short* h_bf   = (unsigned short*)(c_cur + (size_t)4096 * 300);  // 4096*320
  unsigned short* WT     = h_bf   + (size_t)4096 * KP;   // 1200*320
  unsigned short* WfhT   = WT     + (size_t)1200 * KP;   // 300*320
  unsigned short* WiouhT = WfhT   + (size_t)300 * KP;    // 900*320
  unsigned short* hsb_bf = WiouhT + (size_t)900 * KP;    // 585*320

  // P: bf16 weight transposes + pads
  prep_kernel<<<2693, 256, 0, stream>>>(W_ioux, W_fx, W_fh, W_iouh,
      WT, WfhT, WiouhT, h_bf, hsb_bf);
  // K0: MFMA X-GEMM (gather+convert inline)
  fx_mfma<<<74 * 19, 256, 0, stream>>>(tokens, embed, WT, b_ioux, b_fx, b_iouh,
      xiou, fxo, c_cur, h_bf, hsb, hsb_bf);
  // K1: fcb leaf (4096 children -> parents 73..584)
  fcb_mfma<<<64 * 19, 256, 0, stream>>>(4096, 73, h_bf, WfhT, c_cur, b_fh, fxo, fcb);
  // K2: ig 512 (nodes 73..584 -> parents 9..72); h/c rows 0..511
  ig_mfma<<<8 * 19, 256, 0, stream>>>(512, 73, 9, hsb_bf, WiouhT, xiou, b_iouh, fcb,
      c_cur, h_bf, hsb, hsb_bf);
  // K3: fcb 512 (children rows 0..511 -> parents 9..72)
  fcb_mfma<<<8 * 19, 256, 0, stream>>>(512, 9, h_bf, WfhT, c_cur, b_fh, fxo, fcb);
  // K4: ig 64 (nodes 9..72 -> parents 1..8); h/c rows 0..63
  ig_mfma<<<19, 256, 0, stream>>>(64, 9, 1, hsb_bf, WiouhT, xiou, b_iouh, fcb,
      c_cur, h_bf, hsb, hsb_bf);
  // K5: merged fcb64 + ig8 (nodes 1..8); h/c -> rows 64..71
  t5_kernel<<<19, 256, 0, stream>>>(h_bf, WfhT, c_cur, b_fh, fxo, fcb,
      hsb_bf, WiouhT, xiou, b_iouh,
      c_cur + (size_t)64 * 300, h_bf + (size_t)64 * KP, hsb, hsb_bf);
  // K6: merged fcb8 + root iou/gates; root h -> out[42..], c_root -> row 72
  t6_kernel<<<19, 256, 0, stream>>>(h_bf + (size_t)64 * KP, WfhT,
      c_cur + (size_t)64 * 300, b_fh, fxo, fcb,
      hsb_bf, WiouhT, xiou, b_iouh,
      c_cur + (size_t)72 * 300, hsb, hsb_bf, out);
  // K7: W_lin head -> out[0..41]
  head_kernel<<<1, 256, 0, stream>>>(c_cur + (size_t)72 * 300, W_lin, b_lin, out);
}